// Round 1
// baseline (1255.618 us; speedup 1.0000x reference)
//
#include <hip/hip_runtime.h>
#include <math.h>

#define PI_F 3.14159265358979323846f

// ---------------------------------------------------------------- FFT core
// 512-point radix-2 DIT FFT over LDS arrays re/im (bit-reversed input order).
// 256 threads, one butterfly per thread per stage.
__device__ __forceinline__ void fft512(float* re, float* im,
                                       const float* twr, const float* twi, int t) {
#pragma unroll
  for (int s = 0; s < 9; ++s) {
    __syncthreads();
    int h  = 1 << s;
    int j  = t & (h - 1);
    int i1 = ((t >> s) << (s + 1)) + j;
    int i2 = i1 + h;
    int ti = j << (8 - s);            // index into exp(-2*pi*i*k/512) table
    float wr = twr[ti], wi = twi[ti];
    float ur = re[i1], ui = im[i1];
    float vr = re[i2], vi = im[i2];
    float tr = vr * wr - vi * wi;
    float tq = vr * wi + vi * wr;
    re[i1] = ur + tr; im[i1] = ui + tq;
    re[i2] = ur - tr; im[i2] = ui - tq;
  }
}

__device__ __forceinline__ void init_tw(float* twr, float* twi, int t) {
  float s, c;
  sincosf(-2.0f * PI_F * (float)t * (1.0f / 512.0f), &s, &c);
  twr[t] = c; twi[t] = s;
}

// ------------------------------------------------- K1: gray + row FFT
// grid (512 rows, 64 batch), 256 threads. Writes G[b][r][k] (complex).
__global__ __launch_bounds__(256) void k_rowfft(const float* __restrict__ x,
                                                float2* __restrict__ G) {
  __shared__ float re[512], im[512], twr[256], twi[256];
  int t = threadIdx.x;
  int r = blockIdx.x;
  int b = blockIdx.y;
  const float* xb = x + ((size_t)b * 3 * 512 + r) * 512;  // x[b][0][r][0]
  float a0 = 0.299f * xb[t]       + 0.587f * xb[262144 + t]       + 0.114f * xb[524288 + t];
  float a1 = 0.299f * xb[t + 256] + 0.587f * xb[262144 + t + 256] + 0.114f * xb[524288 + t + 256];
  int r0 = __brev((unsigned)t) >> 23;
  int r1 = __brev((unsigned)(t + 256)) >> 23;
  re[r0] = a0; im[r0] = 0.0f;
  re[r1] = a1; im[r1] = 0.0f;
  init_tw(twr, twi, t);
  fft512(re, im, twr, twi, t);
  float2* Gr = G + ((size_t)b * 512 + r) * 512;
  Gr[t]       = make_float2(re[t],       im[t]);
  Gr[t + 256] = make_float2(re[t + 256], im[t + 256]);
}

// ------------------------------------------------- K1.5: in-place transpose of G (per batch)
// grid (16,16,64), block (32,8). Swaps tile (ti,tj) with (tj,ti).
__global__ __launch_bounds__(256) void k_transpose(float2* __restrict__ G) {
  int tj = blockIdx.x, ti = blockIdx.y;
  if (tj < ti) return;
  int b = blockIdx.z;
  __shared__ float2 ta[32][33];
  __shared__ float2 tb[32][33];
  float2* Gb = G + (size_t)b * 262144;
  int tx = threadIdx.x, ty = threadIdx.y;
  int y0 = ti * 32, x0 = tj * 32;
#pragma unroll
  for (int i = 0; i < 32; i += 8) {
    ta[ty + i][tx] = Gb[(size_t)(y0 + ty + i) * 512 + x0 + tx];
    tb[ty + i][tx] = Gb[(size_t)(x0 + ty + i) * 512 + y0 + tx];
  }
  __syncthreads();
#pragma unroll
  for (int i = 0; i < 32; i += 8) {
    Gb[(size_t)(y0 + ty + i) * 512 + x0 + tx] = tb[tx][ty + i];
    Gb[(size_t)(x0 + ty + i) * 512 + y0 + tx] = ta[tx][ty + i];
  }
}

// ------------------------------------------------- K2: column FFT + mag/log1p/fftshift + stats
// After transpose, G[b][kc][r]. Block per (kc,b). Writes S[b][v][u] = logm[b][u][v]
// (u contiguous), accumulates per-image sum/sumsq (double atomics).
__global__ __launch_bounds__(256) void k_colfft(const float2* __restrict__ G,
                                                float* __restrict__ S,
                                                double* __restrict__ stats) {
  __shared__ float re[512], im[512], twr[256], twi[256];
  int t  = threadIdx.x;
  int kc = blockIdx.x;
  int b  = blockIdx.y;
  const float2* Gc = G + ((size_t)b * 512 + kc) * 512;
  float2 v0 = Gc[t], v1 = Gc[t + 256];
  int r0 = __brev((unsigned)t) >> 23;
  int r1 = __brev((unsigned)(t + 256)) >> 23;
  re[r0] = v0.x; im[r0] = v0.y;
  re[r1] = v1.x; im[r1] = v1.y;
  init_tw(twr, twi, t);
  fft512(re, im, twr, twi, t);
  float m0 = log1pf(sqrtf(re[t] * re[t] + im[t] * im[t]));               // kr = t
  float m1 = log1pf(sqrtf(re[t + 256] * re[t + 256] + im[t + 256] * im[t + 256])); // kr = t+256
  int v  = (kc + 256) & 511;
  int u0 = (t + 256) & 511;   // shifted row for kr = t   -> [256,512)
  int u1 = t;                 // shifted row for kr = t+256 -> [0,256)
  float* Sb = S + ((size_t)b * 512 + v) * 512;
  Sb[u0] = m0;
  Sb[u1] = m1;
  // block reduction of sum / sumsq (reuse re/im)
  __syncthreads();
  re[t] = m0 + m1;
  im[t] = m0 * m0 + m1 * m1;
  __syncthreads();
  for (int sft = 128; sft > 0; sft >>= 1) {
    if (t < sft) { re[t] += re[t + sft]; im[t] += im[t + sft]; }
    __syncthreads();
  }
  if (t == 0) {
    atomicAdd(&stats[2 * b],     (double)re[0]);
    atomicAdd(&stats[2 * b + 1], (double)im[0]);
  }
}

__global__ void k_zero_stats(double* stats) {
  stats[threadIdx.x] = 0.0;   // 128 threads: 64 * {sum, sumsq}
}

__global__ void k_stats(const double* __restrict__ stats, float2* __restrict__ muinv) {
  int i = threadIdx.x;  // 64
  double n  = 262144.0;
  double mu = stats[2 * i] / n;
  double va = stats[2 * i + 1] / n - mu * mu;
  if (va < 0.0) va = 0.0;
  double sd = sqrt(va);
  muinv[i] = make_float2((float)mu, (float)(1.0 / (sd + 1e-8)));
}

// ------------------------------------------------- K4: conv1(5x5,s2,p2) + BN + ReLU + maxpool2
// Input f[h][w] = (S[b][w][h]-mu)*inv (1 channel). Output h1[b][32][128][128].
// Block: 16x16 pooled tile, all 32 oc. Pool commutes with BN+ReLU (inv>0).
#define TS1 68
__global__ __launch_bounds__(256) void k_conv1(
    const float* __restrict__ S, const float2* __restrict__ muinv,
    const float* __restrict__ w, const float* __restrict__ cb,
    const float* __restrict__ g, const float* __restrict__ bb,
    const float* __restrict__ bm, const float* __restrict__ bv,
    float* __restrict__ h1) {
  __shared__ float tile[67 * TS1];
  int b = blockIdx.y;
  int by = blockIdx.x >> 3, bx = blockIdx.x & 7;
  int y0 = by * 16, x0 = bx * 16;
  int h0 = 4 * y0 - 2, w0 = 4 * x0 - 2;
  float2 mi = muinv[b];
  const float* Sb = S + (size_t)b * 262144;
  for (int idx = threadIdx.x; idx < 67 * 67; idx += 256) {
    int wl = idx / 67, hl = idx - wl * 67;
    int hh = h0 + hl, ww = w0 + wl;
    float val = 0.0f;
    if (hh >= 0 && hh < 512 && ww >= 0 && ww < 512)
      val = (Sb[(size_t)ww * 512 + hh] - mi.x) * mi.y;
    tile[wl * TS1 + hl] = val;
  }
  __syncthreads();
  int ty = threadIdx.x >> 4, tx = threadIdx.x & 15;
  float in[7][7];
#pragma unroll
  for (int j = 0; j < 7; ++j)
#pragma unroll
    for (int i = 0; i < 7; ++i)
      in[i][j] = tile[(4 * tx + j) * TS1 + 4 * ty + i];
  int Y = y0 + ty, X = x0 + tx;
  for (int oc = 0; oc < 32; ++oc) {
    const float* wo = w + oc * 25;
    float a00 = 0.f, a01 = 0.f, a10 = 0.f, a11 = 0.f;
#pragma unroll
    for (int dy = 0; dy < 5; ++dy)
#pragma unroll
      for (int dx = 0; dx < 5; ++dx) {
        float wv = wo[dy * 5 + dx];
        a00 = fmaf(wv, in[dy][dx], a00);
        a01 = fmaf(wv, in[dy][dx + 2], a01);
        a10 = fmaf(wv, in[dy + 2][dx], a10);
        a11 = fmaf(wv, in[dy + 2][dx + 2], a11);
      }
    float m   = fmaxf(fmaxf(a00, a01), fmaxf(a10, a11));
    float inv = g[oc] / sqrtf(bv[oc] + 1e-5f);
    float sh  = cb[oc] * inv + bb[oc] - bm[oc] * inv;
    h1[(((size_t)b * 32 + oc) * 128 + Y) * 128 + X] = fmaxf(m * inv + sh, 0.0f);
  }
}

// ------------------------------------------------- K5: conv2(3x3,s2,p1,32->64) + BN + ReLU + maxpool2
// Input h1[b][32][128][128], output h2[b][64][32][32].
// Block: 8x8 pooled tile, 16 oc (4 waves x 4 oc). ic staged in chunks of 8.
#define TS2 36
__global__ __launch_bounds__(256) void k_conv2(
    const float* __restrict__ h1, const float* __restrict__ w,
    const float* __restrict__ cb, const float* __restrict__ g,
    const float* __restrict__ bb, const float* __restrict__ bm,
    const float* __restrict__ bv, float* __restrict__ h2) {
  __shared__ __attribute__((aligned(16))) float tile[8 * 33 * TS2];
  int tid = threadIdx.x;
  int b = blockIdx.z, ocb = blockIdx.y;
  int ty0 = (blockIdx.x >> 2) * 8, tx0 = (blockIdx.x & 3) * 8;
  int wv = tid >> 6, pos = tid & 63;
  int py = pos >> 3, px = pos & 7;
  int Y = ty0 + py, X = tx0 + px;
  int iy0 = 4 * ty0 - 1, ix0 = 4 * tx0 - 1;
  float acc[4][4];
#pragma unroll
  for (int q = 0; q < 4; ++q)
#pragma unroll
    for (int p = 0; p < 4; ++p) acc[q][p] = 0.0f;

  for (int ict = 0; ict < 4; ++ict) {
    __syncthreads();
    for (int idx = tid; idx < 8 * 33 * 33; idx += 256) {
      int ic = idx / 1089;
      int rem = idx - ic * 1089;
      int rr = rem / 33, cc = rem - rr * 33;
      int iy = iy0 + rr, ix = ix0 + cc;
      float v = 0.0f;
      int icg = ict * 8 + ic;
      if (iy >= 0 && iy < 128 && ix >= 0 && ix < 128)
        v = h1[(((size_t)b * 32 + icg) * 128 + iy) * 128 + ix];
      tile[(ic * 33 + rr) * TS2 + cc] = v;
    }
    __syncthreads();
    int rbase = 4 * py, cbase = 4 * px;
    for (int ic = 0; ic < 8; ++ic) {
      float in[5][5];
#pragma unroll
      for (int i = 0; i < 5; ++i) {
        const float4* r4 = reinterpret_cast<const float4*>(&tile[(ic * 33 + rbase + i) * TS2 + cbase]);
        float4 a = r4[0];
        in[i][0] = a.x; in[i][1] = a.y; in[i][2] = a.z; in[i][3] = a.w;
        in[i][4] = tile[(ic * 33 + rbase + i) * TS2 + cbase + 4];
      }
#pragma unroll
      for (int q = 0; q < 4; ++q) {
        int oc = ocb * 16 + wv * 4 + q;
        const float* wp = w + ((size_t)oc * 32 + ict * 8 + ic) * 9;
#pragma unroll
        for (int pp = 0; pp < 4; ++pp) {
          int pyy = pp >> 1, pxx = pp & 1;
#pragma unroll
          for (int dy = 0; dy < 3; ++dy)
#pragma unroll
            for (int dx = 0; dx < 3; ++dx)
              acc[q][pp] = fmaf(wp[dy * 3 + dx], in[2 * pyy + dy][2 * pxx + dx], acc[q][pp]);
        }
      }
    }
  }
#pragma unroll
  for (int q = 0; q < 4; ++q) {
    int oc = ocb * 16 + wv * 4 + q;
    float m   = fmaxf(fmaxf(acc[q][0], acc[q][1]), fmaxf(acc[q][2], acc[q][3]));
    float inv = g[oc] / sqrtf(bv[oc] + 1e-5f);
    float sh  = cb[oc] * inv + bb[oc] - bm[oc] * inv;
    h2[(((size_t)b * 64 + oc) * 32 + Y) * 32 + X] = fmaxf(m * inv + sh, 0.0f);
  }
}

// ------------------------------------------------- K6: conv3(3x3,s2,p1,64->128) + BN + ReLU + GAP
// Input h2[b][64][32][32], output gap[b][128].
// Block: 16x16 conv positions, 8 oc; grid (16 ocg, 64 b).
#define TS3 34
__global__ __launch_bounds__(256) void k_conv3(
    const float* __restrict__ h2, const float* __restrict__ w,
    const float* __restrict__ cb, const float* __restrict__ g,
    const float* __restrict__ bb, const float* __restrict__ bm,
    const float* __restrict__ bv, float* __restrict__ gap) {
  __shared__ __attribute__((aligned(16))) float tile[8 * 33 * TS3];
  __shared__ float red[256];
  int tid = threadIdx.x;
  int ocg = blockIdx.x, b = blockIdx.y;
  int cy = tid >> 4, cx = tid & 15;
  float acc[8];
#pragma unroll
  for (int q = 0; q < 8; ++q) acc[q] = 0.0f;

  for (int ict = 0; ict < 8; ++ict) {
    __syncthreads();
    for (int idx = tid; idx < 8 * 33 * 33; idx += 256) {
      int ic = idx / 1089;
      int rem = idx - ic * 1089;
      int rr = rem / 33, cc = rem - rr * 33;
      int iy = rr - 1, ix = cc - 1;
      float v = 0.0f;
      int icg = ict * 8 + ic;
      if (iy >= 0 && iy < 32 && ix >= 0 && ix < 32)
        v = h2[(((size_t)b * 64 + icg) * 32 + iy) * 32 + ix];
      tile[(ic * 33 + rr) * TS3 + cc] = v;
    }
    __syncthreads();
    for (int ic = 0; ic < 8; ++ic) {
      float in[3][3];
#pragma unroll
      for (int i = 0; i < 3; ++i) {
        const float2* r2 = reinterpret_cast<const float2*>(&tile[(ic * 33 + 2 * cy + i) * TS3 + 2 * cx]);
        float2 a = r2[0];
        in[i][0] = a.x; in[i][1] = a.y;
        in[i][2] = tile[(ic * 33 + 2 * cy + i) * TS3 + 2 * cx + 2];
      }
#pragma unroll
      for (int q = 0; q < 8; ++q) {
        int oc = ocg * 8 + q;
        const float* wp = w + ((size_t)oc * 64 + ict * 8 + ic) * 9;
#pragma unroll
        for (int i = 0; i < 3; ++i)
#pragma unroll
          for (int j = 0; j < 3; ++j)
            acc[q] = fmaf(wp[i * 3 + j], in[i][j], acc[q]);
      }
    }
  }
  for (int q = 0; q < 8; ++q) {
    int oc = ocg * 8 + q;
    float inv = g[oc] / sqrtf(bv[oc] + 1e-5f);
    float sh  = cb[oc] * inv + bb[oc] - bm[oc] * inv;
    float val = fmaxf(acc[q] * inv + sh, 0.0f);
    __syncthreads();
    red[tid] = val;
    __syncthreads();
    for (int s = 128; s > 0; s >>= 1) {
      if (tid < s) red[tid] += red[tid + s];
      __syncthreads();
    }
    if (tid == 0) gap[(size_t)b * 128 + oc] = red[0] * (1.0f / 256.0f);
  }
}

// ------------------------------------------------- K7: FC1+ReLU+FC2+ReLU
__global__ __launch_bounds__(256) void k_fc(
    const float* __restrict__ gap,
    const float* __restrict__ w1, const float* __restrict__ b1,
    const float* __restrict__ w2, const float* __restrict__ b2,
    float* __restrict__ out) {
  __shared__ float gv[128], hv[256];
  int b = blockIdx.x, t = threadIdx.x;
  if (t < 128) gv[t] = gap[(size_t)b * 128 + t];
  __syncthreads();
  float a1 = b1[t];
  const float* wr = w1 + (size_t)t * 128;
  for (int k = 0; k < 128; ++k) a1 = fmaf(wr[k], gv[k], a1);
  hv[t] = fmaxf(a1, 0.0f);
  __syncthreads();
  if (t < 128) {
    float a2 = b2[t];
    const float* wr2 = w2 + (size_t)t * 256;
    for (int k = 0; k < 256; ++k) a2 = fmaf(wr2[k], hv[k], a2);
    out[(size_t)b * 128 + t] = fmaxf(a2, 0.0f);
  }
}

// ================================================================ launch
extern "C" void kernel_launch(void* const* d_in, const int* in_sizes, int n_in,
                              void* d_out, int out_size, void* d_ws, size_t ws_size,
                              hipStream_t stream) {
  (void)in_sizes; (void)n_in; (void)out_size; (void)ws_size;
  const float* x   = (const float*)d_in[0];
  const float* c1w = (const float*)d_in[1];
  const float* c1b = (const float*)d_in[2];
  const float* b1g = (const float*)d_in[3];
  const float* b1b = (const float*)d_in[4];
  const float* b1m = (const float*)d_in[5];
  const float* b1v = (const float*)d_in[6];
  const float* c2w = (const float*)d_in[7];
  const float* c2b = (const float*)d_in[8];
  const float* b2g = (const float*)d_in[9];
  const float* b2b = (const float*)d_in[10];
  const float* b2m = (const float*)d_in[11];
  const float* b2v = (const float*)d_in[12];
  const float* c3w = (const float*)d_in[13];
  const float* c3b = (const float*)d_in[14];
  const float* b3g = (const float*)d_in[15];
  const float* b3b = (const float*)d_in[16];
  const float* b3m = (const float*)d_in[17];
  const float* b3v = (const float*)d_in[18];
  const float* f1w = (const float*)d_in[19];
  const float* f1b = (const float*)d_in[20];
  const float* f2w = (const float*)d_in[21];
  const float* f2b = (const float*)d_in[22];
  float* out = (float*)d_out;

  char* ws = (char*)d_ws;
  // Workspace layout (peak ~192 MiB):
  //   [0, 128MiB)   G (complex rowFFT, in-place transposed)  -- later reused as h1
  //   [128, 192MiB) S (transposed logm)                       -- later reused as h2
  //   then: stats (64x2 double), muinv (64 float2), gap (64x128 float)
  float2* G     = (float2*)(ws + 0);
  float*  S     = (float*) (ws + 134217728ull);
  double* stats = (double*)(ws + 201326592ull);
  float2* muinv = (float2*)(ws + 201327616ull);
  float*  gap   = (float*) (ws + 201328128ull);
  float*  h1    = (float*) (ws + 0);
  float*  h2    = (float*) (ws + 134217728ull);

  k_zero_stats<<<1, 128, 0, stream>>>(stats);
  k_rowfft   <<<dim3(512, 64), 256, 0, stream>>>(x, G);
  k_transpose<<<dim3(16, 16, 64), dim3(32, 8), 0, stream>>>(G);
  k_colfft   <<<dim3(512, 64), 256, 0, stream>>>(G, S, stats);
  k_stats    <<<1, 64, 0, stream>>>(stats, muinv);
  k_conv1    <<<dim3(64, 64), 256, 0, stream>>>(S, muinv, c1w, c1b, b1g, b1b, b1m, b1v, h1);
  k_conv2    <<<dim3(16, 4, 64), 256, 0, stream>>>(h1, c2w, c2b, b2g, b2b, b2m, b2v, h2);
  k_conv3    <<<dim3(16, 64), 256, 0, stream>>>(h2, c3w, c3b, b3g, b3b, b3m, b3v, gap);
  k_fc       <<<64, 256, 0, stream>>>(gap, f1w, f1b, f2w, f2b, out);
}

// Round 2
// 1162.433 us; speedup vs baseline: 1.0802x; 1.0802x over previous
//
#include <hip/hip_runtime.h>
#include <math.h>

#define PI_F 3.14159265358979323846f
#define KS 258   // padded column count of half-spectrum G (k in [0,256], stride 258)

// ---------------------------------------------------------------- FFT core
// 512-point radix-2 DIT FFT over LDS arrays re/im (bit-reversed input order).
// 256 threads, one butterfly per thread per stage. Natural-order output.
__device__ __forceinline__ void fft512(float* re, float* im,
                                       const float* twr, const float* twi, int t) {
#pragma unroll
  for (int s = 0; s < 9; ++s) {
    __syncthreads();
    int h  = 1 << s;
    int j  = t & (h - 1);
    int i1 = ((t >> s) << (s + 1)) + j;
    int i2 = i1 + h;
    int ti = j << (8 - s);
    float wr = twr[ti], wi = twi[ti];
    float ur = re[i1], ui = im[i1];
    float vr = re[i2], vi = im[i2];
    float tr = vr * wr - vi * wi;
    float tq = vr * wi + vi * wr;
    re[i1] = ur + tr; im[i1] = ui + tq;
    re[i2] = ur - tr; im[i2] = ui - tq;
  }
}

__device__ __forceinline__ void init_tw(float* twr, float* twi, int t) {
  float s, c;
  sincosf(-2.0f * PI_F * (float)t * (1.0f / 512.0f), &s, &c);
  twr[t] = c; twi[t] = s;
}

// ------------------------------------------------- K1: gray + paired-row FFT (Hermitian pack)
// Rows are real: FFT rows r0=2q (re) and r1=2q+1 (im) together; unpack via
// A[k]=(Z[k]+Z*[-k])/2, B[k]=(Z[k]-Z*[-k])/(2i). Store only k in [0,256].
// grid (256 pairs, 64 batch). G[b][r][k], row stride KS float2.
__global__ __launch_bounds__(256) void k_rowfft(const float* __restrict__ x,
                                                float2* __restrict__ G) {
  __shared__ float re[512], im[512], twr[256], twi[256];
  int t = threadIdx.x;
  int q = blockIdx.x;
  int b = blockIdx.y;
  int r0 = 2 * q;
  const float* xb = x + ((size_t)b * 3 * 512 + r0) * 512;
  float a0 = 0.299f * xb[t]           + 0.587f * xb[262144 + t]           + 0.114f * xb[524288 + t];
  float a1 = 0.299f * xb[t + 256]     + 0.587f * xb[262144 + t + 256]     + 0.114f * xb[524288 + t + 256];
  float c0 = 0.299f * xb[512 + t]     + 0.587f * xb[262656 + t]           + 0.114f * xb[524800 + t];
  float c1 = 0.299f * xb[512 + t + 256] + 0.587f * xb[262656 + t + 256]   + 0.114f * xb[524800 + t + 256];
  int rv0 = __brev((unsigned)t) >> 23;
  int rv1 = __brev((unsigned)(t + 256)) >> 23;
  re[rv0] = a0; im[rv0] = c0;
  re[rv1] = a1; im[rv1] = c1;
  init_tw(twr, twi, t);
  fft512(re, im, twr, twi, t);
  __syncthreads();
  float2* G0 = G + ((size_t)b * 512 + r0) * KS;
  float2* G1 = G0 + KS;
  for (int k = t; k <= 256; k += 256) {   // t==0 handles k=0 and k=256
    int mk = (512 - k) & 511;
    float zr = re[k], zi = im[k];
    float mr = re[mk], mi = im[mk];
    G0[k] = make_float2(0.5f * (zr + mr), 0.5f * (zi - mi));
    G1[k] = make_float2(0.5f * (zi + mi), 0.5f * (mr - zr));
  }
}

// ------------------------------------------------- K1.5: out-of-place transpose G -> GT
// G[b][r][k] (512 x KS) -> GT[b][k][r] (KS x 512). grid (9,16,64), block (32,8).
__global__ __launch_bounds__(256) void k_transpose(const float2* __restrict__ G,
                                                   float2* __restrict__ GT) {
  __shared__ float2 ta[32][33];
  int kt = blockIdx.x, rt = blockIdx.y, b = blockIdx.z;
  int tx = threadIdx.x, ty = threadIdx.y;
  int k0 = kt * 32, r0 = rt * 32;
  const float2* Gb = G + (size_t)b * 512 * KS;
  float2* GTb = GT + (size_t)b * KS * 512;
#pragma unroll
  for (int i = 0; i < 32; i += 8) {
    int k = k0 + tx;
    float2 v = make_float2(0.0f, 0.0f);
    if (k < KS) v = Gb[(size_t)(r0 + ty + i) * KS + k];
    ta[ty + i][tx] = v;
  }
  __syncthreads();
#pragma unroll
  for (int i = 0; i < 32; i += 8) {
    int k = k0 + ty + i;
    if (k < KS) GTb[(size_t)k * 512 + r0 + tx] = ta[tx][ty + i];
  }
}

// ------------------------------------------------- K2: column FFT + mag/log1p/fftshift + mirror + stats
// Columns kc in [0,256] only; |F[u,v]|=|F[-u,-v]| fills the rest.
// S[b][v][u] = shifted logm with u contiguous. grid (257, 64).
__global__ __launch_bounds__(256) void k_colfft(const float2* __restrict__ GT,
                                                float* __restrict__ S,
                                                double* __restrict__ stats) {
  __shared__ float re[512], im[512], twr[256], twi[256];
  int t  = threadIdx.x;
  int kc = blockIdx.x;
  int b  = blockIdx.y;
  const float2* Gc = GT + ((size_t)b * KS + kc) * 512;
  float2 v0 = Gc[t], v1 = Gc[t + 256];
  int rv0 = __brev((unsigned)t) >> 23;
  int rv1 = __brev((unsigned)(t + 256)) >> 23;
  re[rv0] = v0.x; im[rv0] = v0.y;
  re[rv1] = v1.x; im[rv1] = v1.y;
  init_tw(twr, twi, t);
  fft512(re, im, twr, twi, t);
  float m0 = log1pf(sqrtf(re[t] * re[t] + im[t] * im[t]));                     // kr = t
  float m1 = log1pf(sqrtf(re[t + 256] * re[t + 256] + im[t + 256] * im[t + 256])); // kr = t+256
  int v = (kc + 256) & 511;
  float* Sb = S + (size_t)b * 262144;
  Sb[(size_t)v * 512 + t + 256] = m0;   // u0 = t+256
  Sb[(size_t)v * 512 + t]       = m1;   // u1 = t
  bool mir = (kc >= 1) && (kc <= 255);
  if (mir) {
    int vp = 256 - kc;
    Sb[(size_t)vp * 512 + ((256 - t) & 511)] = m0;
    Sb[(size_t)vp * 512 + ((512 - t) & 511)] = m1;
  }
  __syncthreads();
  re[t] = m0 + m1;
  im[t] = m0 * m0 + m1 * m1;
  __syncthreads();
  for (int s = 128; s > 0; s >>= 1) {
    if (t < s) { re[t] += re[t + s]; im[t] += im[t + s]; }
    __syncthreads();
  }
  if (t == 0) {
    double wgt = mir ? 2.0 : 1.0;
    atomicAdd(&stats[2 * b],     wgt * (double)re[0]);
    atomicAdd(&stats[2 * b + 1], wgt * (double)im[0]);
  }
}

__global__ void k_zero_stats(double* stats) {
  stats[threadIdx.x] = 0.0;   // 128 threads: 64 * {sum, sumsq}
}

__global__ void k_stats(const double* __restrict__ stats, float2* __restrict__ muinv) {
  int i = threadIdx.x;  // 64
  double n  = 262144.0;
  double mu = stats[2 * i] / n;
  double va = stats[2 * i + 1] / n - mu * mu;
  if (va < 0.0) va = 0.0;
  double sd = sqrt(va);
  muinv[i] = make_float2((float)mu, (float)(1.0 / (sd + 1e-8)));
}

// ------------------------------------------------- K4: conv1(5x5,s2,p2) + BN + ReLU + maxpool2
// Input f[h][w] = (S[b][w][h]-mu)*inv (1 channel). Output h1[b][32][128][128].
#define TS1 68
__global__ __launch_bounds__(256) void k_conv1(
    const float* __restrict__ S, const float2* __restrict__ muinv,
    const float* __restrict__ w, const float* __restrict__ cb,
    const float* __restrict__ g, const float* __restrict__ bb,
    const float* __restrict__ bm, const float* __restrict__ bv,
    float* __restrict__ h1) {
  __shared__ float tile[67 * TS1];
  int b = blockIdx.y;
  int by = blockIdx.x >> 3, bx = blockIdx.x & 7;
  int y0 = by * 16, x0 = bx * 16;
  int h0 = 4 * y0 - 2, w0 = 4 * x0 - 2;
  float2 mi = muinv[b];
  const float* Sb = S + (size_t)b * 262144;
  for (int idx = threadIdx.x; idx < 67 * 67; idx += 256) {
    int wl = idx / 67, hl = idx - wl * 67;
    int hh = h0 + hl, ww = w0 + wl;
    float val = 0.0f;
    if (hh >= 0 && hh < 512 && ww >= 0 && ww < 512)
      val = (Sb[(size_t)ww * 512 + hh] - mi.x) * mi.y;
    tile[wl * TS1 + hl] = val;
  }
  __syncthreads();
  int ty = threadIdx.x >> 4, tx = threadIdx.x & 15;
  float in[7][7];
#pragma unroll
  for (int j = 0; j < 7; ++j)
#pragma unroll
    for (int i = 0; i < 7; ++i)
      in[i][j] = tile[(4 * tx + j) * TS1 + 4 * ty + i];
  int Y = y0 + ty, X = x0 + tx;
  for (int oc = 0; oc < 32; ++oc) {
    const float* wo = w + oc * 25;
    float a00 = 0.f, a01 = 0.f, a10 = 0.f, a11 = 0.f;
#pragma unroll
    for (int dy = 0; dy < 5; ++dy)
#pragma unroll
      for (int dx = 0; dx < 5; ++dx) {
        float wv = wo[dy * 5 + dx];
        a00 = fmaf(wv, in[dy][dx], a00);
        a01 = fmaf(wv, in[dy][dx + 2], a01);
        a10 = fmaf(wv, in[dy + 2][dx], a10);
        a11 = fmaf(wv, in[dy + 2][dx + 2], a11);
      }
    float m   = fmaxf(fmaxf(a00, a01), fmaxf(a10, a11));
    float inv = g[oc] / sqrtf(bv[oc] + 1e-5f);
    float sh  = cb[oc] * inv + bb[oc] - bm[oc] * inv;
    h1[(((size_t)b * 32 + oc) * 128 + Y) * 128 + X] = fmaxf(m * inv + sh, 0.0f);
  }
}

// ------------------------------------------------- K5: conv2(3x3,s2,p1,32->64) + BN + ReLU + maxpool2
// One conv position per thread (16x16 conv tile), 32 oc in registers,
// 2x2 maxpool via shfl_xor(1)/shfl_xor(16). LDS reads are exact 2-way (free).
#define TS2 36
__global__ __launch_bounds__(256) void k_conv2(
    const float* __restrict__ h1, const float* __restrict__ w,
    const float* __restrict__ cb, const float* __restrict__ g,
    const float* __restrict__ bb, const float* __restrict__ bm,
    const float* __restrict__ bv, float* __restrict__ h2) {
  __shared__ float tile[8 * 33 * TS2];   // 38016 B -> 4 blocks/CU
  int tid = threadIdx.x;
  int b = blockIdx.z, ocb = blockIdx.y;
  int ty0 = (blockIdx.x >> 2) * 16, tx0 = (blockIdx.x & 3) * 16;  // conv coords [0,64)
  int py = tid >> 4, px = tid & 15;
  int iy0 = 2 * ty0 - 1, ix0 = 2 * tx0 - 1;
  float acc[32];
#pragma unroll
  for (int q = 0; q < 32; ++q) acc[q] = 0.0f;

  for (int ict = 0; ict < 4; ++ict) {
    __syncthreads();
    for (int idx = tid; idx < 8 * 33 * 33; idx += 256) {
      int ic = idx / 1089;
      int rem = idx - ic * 1089;
      int rr = rem / 33, cc = rem - rr * 33;
      int iy = iy0 + rr, ix = ix0 + cc;
      float v = 0.0f;
      int icg = ict * 8 + ic;
      if (iy >= 0 && iy < 128 && ix >= 0 && ix < 128)
        v = h1[(((size_t)b * 32 + icg) * 128 + iy) * 128 + ix];
      tile[(ic * 33 + rr) * TS2 + cc] = v;
    }
    __syncthreads();
    int rbase = 2 * py, cbase = 2 * px;
    for (int ic = 0; ic < 8; ++ic) {
      float in[3][3];
#pragma unroll
      for (int i = 0; i < 3; ++i)
#pragma unroll
        for (int j = 0; j < 3; ++j)
          in[i][j] = tile[(ic * 33 + rbase + i) * TS2 + cbase + j];
      int icg = ict * 8 + ic;
      const float* wp = w + ((size_t)(ocb * 32) * 32 + icg) * 9;
#pragma unroll
      for (int q = 0; q < 32; ++q) {
        const float* wq = wp + (size_t)q * 32 * 9;
#pragma unroll
        for (int dy = 0; dy < 3; ++dy)
#pragma unroll
          for (int dx = 0; dx < 3; ++dx)
            acc[q] = fmaf(wq[dy * 3 + dx], in[dy][dx], acc[q]);
      }
    }
  }
  int Y = ty0 + py, X = tx0 + px;
  bool writer = ((py & 1) == 0) && ((px & 1) == 0);
  int Yp = Y >> 1, Xp = X >> 1;
#pragma unroll
  for (int q = 0; q < 32; ++q) {
    float m = acc[q];
    m = fmaxf(m, __shfl_xor(m, 1));
    m = fmaxf(m, __shfl_xor(m, 16));
    if (writer) {
      int oc = ocb * 32 + q;
      float inv = g[oc] / sqrtf(bv[oc] + 1e-5f);
      float sh  = cb[oc] * inv + bb[oc] - bm[oc] * inv;
      h2[(((size_t)b * 64 + oc) * 32 + Yp) * 32 + Xp] = fmaxf(m * inv + sh, 0.0f);
    }
  }
}

// ------------------------------------------------- K6: conv3(3x3,s2,p1,64->128) + BN + ReLU + GAP
#define TS3 34
__global__ __launch_bounds__(256) void k_conv3(
    const float* __restrict__ h2, const float* __restrict__ w,
    const float* __restrict__ cb, const float* __restrict__ g,
    const float* __restrict__ bb, const float* __restrict__ bm,
    const float* __restrict__ bv, float* __restrict__ gap) {
  __shared__ __attribute__((aligned(16))) float tile[8 * 33 * TS3];
  __shared__ float red[256];
  int tid = threadIdx.x;
  int ocg = blockIdx.x, b = blockIdx.y;
  int cy = tid >> 4, cx = tid & 15;
  float acc[8];
#pragma unroll
  for (int q = 0; q < 8; ++q) acc[q] = 0.0f;

  for (int ict = 0; ict < 8; ++ict) {
    __syncthreads();
    for (int idx = tid; idx < 8 * 33 * 33; idx += 256) {
      int ic = idx / 1089;
      int rem = idx - ic * 1089;
      int rr = rem / 33, cc = rem - rr * 33;
      int iy = rr - 1, ix = cc - 1;
      float v = 0.0f;
      int icg = ict * 8 + ic;
      if (iy >= 0 && iy < 32 && ix >= 0 && ix < 32)
        v = h2[(((size_t)b * 64 + icg) * 32 + iy) * 32 + ix];
      tile[(ic * 33 + rr) * TS3 + cc] = v;
    }
    __syncthreads();
    for (int ic = 0; ic < 8; ++ic) {
      float in[3][3];
#pragma unroll
      for (int i = 0; i < 3; ++i) {
        const float2* r2 = reinterpret_cast<const float2*>(&tile[(ic * 33 + 2 * cy + i) * TS3 + 2 * cx]);
        float2 a = r2[0];
        in[i][0] = a.x; in[i][1] = a.y;
        in[i][2] = tile[(ic * 33 + 2 * cy + i) * TS3 + 2 * cx + 2];
      }
#pragma unroll
      for (int q = 0; q < 8; ++q) {
        int oc = ocg * 8 + q;
        const float* wp = w + ((size_t)oc * 64 + ict * 8 + ic) * 9;
#pragma unroll
        for (int i = 0; i < 3; ++i)
#pragma unroll
          for (int j = 0; j < 3; ++j)
            acc[q] = fmaf(wp[i * 3 + j], in[i][j], acc[q]);
      }
    }
  }
  for (int q = 0; q < 8; ++q) {
    int oc = ocg * 8 + q;
    float inv = g[oc] / sqrtf(bv[oc] + 1e-5f);
    float sh  = cb[oc] * inv + bb[oc] - bm[oc] * inv;
    float val = fmaxf(acc[q] * inv + sh, 0.0f);
    __syncthreads();
    red[tid] = val;
    __syncthreads();
    for (int s = 128; s > 0; s >>= 1) {
      if (tid < s) red[tid] += red[tid + s];
      __syncthreads();
    }
    if (tid == 0) gap[(size_t)b * 128 + oc] = red[0] * (1.0f / 256.0f);
  }
}

// ------------------------------------------------- K7: FC1+ReLU+FC2+ReLU
__global__ __launch_bounds__(256) void k_fc(
    const float* __restrict__ gap,
    const float* __restrict__ w1, const float* __restrict__ b1,
    const float* __restrict__ w2, const float* __restrict__ b2,
    float* __restrict__ out) {
  __shared__ float gv[128], hv[256];
  int b = blockIdx.x, t = threadIdx.x;
  if (t < 128) gv[t] = gap[(size_t)b * 128 + t];
  __syncthreads();
  float a1 = b1[t];
  const float* wr = w1 + (size_t)t * 128;
  for (int k = 0; k < 128; ++k) a1 = fmaf(wr[k], gv[k], a1);
  hv[t] = fmaxf(a1, 0.0f);
  __syncthreads();
  if (t < 128) {
    float a2 = b2[t];
    const float* wr2 = w2 + (size_t)t * 256;
    for (int k = 0; k < 256; ++k) a2 = fmaf(wr2[k], hv[k], a2);
    out[(size_t)b * 128 + t] = fmaxf(a2, 0.0f);
  }
}

// ================================================================ launch
extern "C" void kernel_launch(void* const* d_in, const int* in_sizes, int n_in,
                              void* d_out, int out_size, void* d_ws, size_t ws_size,
                              hipStream_t stream) {
  (void)in_sizes; (void)n_in; (void)out_size; (void)ws_size;
  const float* x   = (const float*)d_in[0];
  const float* c1w = (const float*)d_in[1];
  const float* c1b = (const float*)d_in[2];
  const float* b1g = (const float*)d_in[3];
  const float* b1b = (const float*)d_in[4];
  const float* b1m = (const float*)d_in[5];
  const float* b1v = (const float*)d_in[6];
  const float* c2w = (const float*)d_in[7];
  const float* c2b = (const float*)d_in[8];
  const float* b2g = (const float*)d_in[9];
  const float* b2b = (const float*)d_in[10];
  const float* b2m = (const float*)d_in[11];
  const float* b2v = (const float*)d_in[12];
  const float* c3w = (const float*)d_in[13];
  const float* c3b = (const float*)d_in[14];
  const float* b3g = (const float*)d_in[15];
  const float* b3b = (const float*)d_in[16];
  const float* b3m = (const float*)d_in[17];
  const float* b3v = (const float*)d_in[18];
  const float* f1w = (const float*)d_in[19];
  const float* f1b = (const float*)d_in[20];
  const float* f2w = (const float*)d_in[21];
  const float* f2b = (const float*)d_in[22];
  float* out = (float*)d_out;

  char* ws = (char*)d_ws;
  // Workspace layout (peak ~193 MiB):
  //   G  [0,            67,633,152)  half-spectrum row FFT (64 x 512 x 258 float2)
  //   GT [67,633,152,  135,266,304)  transposed G
  //   S  [135,266,304, 202,375,168)  shifted logm, S[b][v][u]
  //   stats/muinv/gap after S
  //   h1 reuses [0, 134,217,728) (G+GT dead after colfft)
  //   h2 reuses S region (S dead after conv1)
  float2* G     = (float2*)(ws + 0);
  float2* GT    = (float2*)(ws + 67633152ull);
  float*  S     = (float*) (ws + 135266304ull);
  double* stats = (double*)(ws + 202375168ull);
  float2* muinv = (float2*)(ws + 202376192ull);
  float*  gap   = (float*) (ws + 202376704ull);
  float*  h1    = (float*) (ws + 0);
  float*  h2    = (float*) (ws + 135266304ull);

  k_zero_stats<<<1, 128, 0, stream>>>(stats);
  k_rowfft   <<<dim3(256, 64), 256, 0, stream>>>(x, G);
  k_transpose<<<dim3(9, 16, 64), dim3(32, 8), 0, stream>>>(G, GT);
  k_colfft   <<<dim3(257, 64), 256, 0, stream>>>(GT, S, stats);
  k_stats    <<<1, 64, 0, stream>>>(stats, muinv);
  k_conv1    <<<dim3(64, 64), 256, 0, stream>>>(S, muinv, c1w, c1b, b1g, b1b, b1m, b1v, h1);
  k_conv2    <<<dim3(16, 2, 64), 256, 0, stream>>>(h1, c2w, c2b, b2g, b2b, b2m, b2v, h2);
  k_conv3    <<<dim3(16, 64), 256, 0, stream>>>(h2, c3w, c3b, b3g, b3b, b3m, b3v, gap);
  k_fc       <<<64, 256, 0, stream>>>(gap, f1w, f1b, f2w, f2b, out);
}